// Round 6
// baseline (70.617 us; speedup 1.0000x reference)
//
#include <hip/hip_runtime.h>

// Batched zero-phase Butterworth filtfilt (order 5), rows of length 8192.
// Persistent blocks: each block processes ROWS=4 rows; the global loads for
// row r+1 are issued (into registers, coalesced float4) right after row r's
// staging barrier, so HBM streaming overlaps row r's compute (T14 async-STAGE).
// Per row, R3's proven structure: each of 256 threads owns a 32-sample chunk,
// warms over chunk tid-1 (pole decay 0.819^32 ~ 1.7e-3 << 8.8e-2 threshold),
// y exchanged through LDS for the backward warmup, own backward chunk from
// registers. LDS: transposed + XOR-swizzled, word(c,i) = i*256 + (c^swz(i)),
// exactly 32768 B, all hot accesses <=2-way (free). Edge threads (tid 0 fwd,
// tid 255 tail/bwd) follow the reference recursion exactly.

#define NN   8192
#define PADL 18
#define LC   32
#define TPB  256
#define ROWS 4

__device__ __forceinline__ int xw(int c, int i) {
    return (i << 8) + (c ^ (((i >> 2) & 7) << 2));
}

// one DF2T step; updates z0..z4, sets yv (10 fma + 1 mul)
#define STEP(xv) do {                               \
    float y_ = fmaf(b0, (xv), z0);                  \
    z0 = fmaf(na1, y_, fmaf(b1, (xv), z1));         \
    z1 = fmaf(na2, y_, fmaf(b2, (xv), z2));         \
    z2 = fmaf(na3, y_, fmaf(b3, (xv), z3));         \
    z3 = fmaf(na4, y_, fmaf(b4, (xv), z4));         \
    z4 = fmaf(na5, y_, b5 * (xv));                  \
    yv = y_;                                        \
} while (0)

__global__ __launch_bounds__(TPB, 4) void GREEN_62869731278967_filtfilt(
    const float* __restrict__ x,
    const float* __restrict__ bc,
    const float* __restrict__ ac,
    const float* __restrict__ zc,
    float* __restrict__ out)
{
    __shared__ float lds[NN];            // 32768 B exactly; reused across rows
    const int tid = threadIdx.x;
    const int row0 = blockIdx.x * ROWS;

    const float b0 = bc[0], b1 = bc[1], b2 = bc[2], b3 = bc[3], b4 = bc[4], b5 = bc[5];
    const float na1 = -ac[1], na2 = -ac[2], na3 = -ac[3], na4 = -ac[4], na5 = -ac[5];
    const float zi0 = zc[0], zi1 = zc[1], zi2 = zc[2], zi3 = zc[3], zi4 = zc[4];

    // staging base for swizzled LDS writes (see derivation in R3/R4):
    // global word j = 1024q + 4*tid + m  ->  lds word Abase + 32q + 256m
    const int Abase = ((tid & 7) << 10) + ((tid >> 3) ^ ((tid & 7) << 2));

    // ---- prologue: load row 0 into registers (coalesced float4) ----
    float4 xnx[8];
    {
        const float* xr = x + (size_t)row0 * NN;
#pragma unroll
        for (int q = 0; q < 8; ++q)
            xnx[q] = *reinterpret_cast<const float4*>(xr + (q << 10) + (tid << 2));
    }

#pragma unroll 1
    for (int r = 0; r < ROWS; ++r) {
        float*       outr = out + (size_t)(row0 + r) * NN;

        // ---- stage current row from regs into swizzled LDS ----
        __syncthreads();                 // prior row's LDS reads complete
#pragma unroll
        for (int q = 0; q < 8; ++q) {
            lds[Abase + (q << 5) + 0]   = xnx[q].x;
            lds[Abase + (q << 5) + 256] = xnx[q].y;
            lds[Abase + (q << 5) + 512] = xnx[q].z;
            lds[Abase + (q << 5) + 768] = xnx[q].w;
        }
        __syncthreads();                 // x ready

        // ---- issue next row's loads NOW; latency hides under this row's compute ----
        if (r + 1 < ROWS) {
            const float* xr = x + (size_t)(row0 + r + 1) * NN;
#pragma unroll
            for (int q = 0; q < 8; ++q)
                xnx[q] = *reinterpret_cast<const float4*>(xr + (q << 10) + (tid << 2));
        }

        // ---- forward: warm over chunk tid-1, filter own chunk -> yreg ----
        float yreg[LC];
        float ytail[PADL];               // only tid == 255 uses
        float z0, z1, z2, z3, z4, yv;
        if (tid == 0) {
            // exact reference path: init zi*ext[0], feed the 18 reflected samples
            const float x0 = lds[xw(0, 0)];
            float v0 = 2.f * x0 - lds[xw(0, PADL)];
            z0 = zi0 * v0; z1 = zi1 * v0; z2 = zi2 * v0; z3 = zi3 * v0; z4 = zi4 * v0;
#pragma unroll
            for (int t = 0; t < PADL; ++t) {
                float v = 2.f * x0 - lds[xw(0, PADL - t)];
                STEP(v);
            }
        } else {
            float v0 = lds[xw(tid - 1, 0)];
            z0 = zi0 * v0; z1 = zi1 * v0; z2 = zi2 * v0; z3 = zi3 * v0; z4 = zi4 * v0;
#pragma unroll
            for (int i = 0; i < LC; ++i) STEP(lds[xw(tid - 1, i)]);
        }
#pragma unroll
        for (int i = 0; i < LC; ++i) { STEP(lds[xw(tid, i)]); yreg[i] = yv; }
        if (tid == TPB - 1) {
            // tail y[8210..8227): ext = 2*xN - x[8190-i]  (chunk 255, elem 30-i)
            const float xN = lds[xw(TPB - 1, 31)];
#pragma unroll
            for (int i = 0; i < PADL; ++i) {
                float v = 2.f * xN - lds[xw(TPB - 1, 30 - i)];
                STEP(v);
                ytail[i] = yv;
            }
        }
        __syncthreads();                 // all forward x-reads done

        // ---- exchange: overwrite LDS chunk tid with y ----
#pragma unroll
        for (int i = 0; i < LC; ++i) lds[xw(tid, i)] = yreg[i];
        __syncthreads();                 // y ready

        // ---- backward: warm descending over chunk tid+1's y, then own from regs ----
        if (tid == TPB - 1) {
            float u0 = ytail[PADL - 1];
            z0 = zi0 * u0; z1 = zi1 * u0; z2 = zi2 * u0; z3 = zi3 * u0; z4 = zi4 * u0;
#pragma unroll
            for (int s = 0; s < PADL; ++s) STEP(ytail[PADL - 1 - s]);
        } else {
            float u0 = lds[xw(tid + 1, LC - 1)];
            z0 = zi0 * u0; z1 = zi1 * u0; z2 = zi2 * u0; z3 = zi3 * u0; z4 = zi4 * u0;
#pragma unroll
            for (int i = 0; i < LC; ++i) STEP(lds[xw(tid + 1, LC - 1 - i)]);
        }
#pragma unroll
        for (int i = 0; i < LC; ++i) { STEP(yreg[LC - 1 - i]); yreg[LC - 1 - i] = yv; }

        // ---- store (float4) ----
#pragma unroll
        for (int q = 0; q < LC / 4; ++q) {
            float4 v;
            v.x = yreg[4 * q + 0];
            v.y = yreg[4 * q + 1];
            v.z = yreg[4 * q + 2];
            v.w = yreg[4 * q + 3];
            *reinterpret_cast<float4*>(outr + tid * LC + 4 * q) = v;
        }
    }
}

extern "C" void kernel_launch(void* const* d_in, const int* in_sizes, int n_in,
                              void* d_out, int out_size, void* d_ws, size_t ws_size,
                              hipStream_t stream) {
    const float* x  = (const float*)d_in[0];
    const float* b  = (const float*)d_in[1];
    const float* a  = (const float*)d_in[2];
    const float* zi = (const float*)d_in[3];
    float* out = (float*)d_out;
    const int rows = in_sizes[0] / NN;           // 4096
    const int blocks = rows / ROWS;              // 1024
    GREEN_62869731278967_filtfilt<<<blocks, TPB, 0, stream>>>(x, b, a, zi, out);
}

// Round 7
// 65.243 us; speedup vs baseline: 1.0824x; 1.0824x over previous
//
#include <hip/hip_runtime.h>
#include <stdint.h>

// Batched zero-phase Butterworth filtfilt (order 5), rows of length 8192.
// One block (256 thr) per row; each thread owns a 32-sample chunk, warms over
// chunk tid-1 (pole decay 0.819^32 ~ 1.7e-3 << 8.8e-2 threshold), y exchanged
// through LDS for the backward warmup, backward own-chunk from registers.
//
// LDS layout (quad-granular XOR swizzle): quad (c,j) of the row lives at word
//   32*c + 4*(j ^ (c&7)),  c = chunk 0..255, j = quad 0..7
// -> every hot access is ds_read_b128/ds_write_b128 at the minimum bank cost;
//    chunk 0 is linear (c&7==0) so exact edge paths use scalar access.
// Staging: __builtin_amdgcn_global_load_lds (16B/lane) with PRE-SWIZZLED
// per-lane global source (linear LDS dest = wave base + 16*lane; the source
// permutation is within 128-B lines -> still fully coalesced).

#define NN   8192
#define PADL 18
#define LC   32
#define TPB  256

typedef uint32_t u32;

__device__ __forceinline__ void gload16(const float* g, float* l) {
    __builtin_amdgcn_global_load_lds(
        (const __attribute__((address_space(1))) u32*)g,
        (__attribute__((address_space(3))) u32*)l, 16, 0, 0);
}

// scalar element e (0..31) of chunk c
__device__ __forceinline__ float SC(const float* lds, int c, int e) {
    return lds[(c << 5) + (((e >> 2) ^ (c & 7)) << 2) + (e & 3)];
}
// quad j (0..7) of chunk c
__device__ __forceinline__ float4 LDQ(const float* lds, int c, int j) {
    return *reinterpret_cast<const float4*>(lds + (c << 5) + ((j ^ (c & 7)) << 2));
}
__device__ __forceinline__ void STQ(float* lds, int c, int j, float4 v) {
    *reinterpret_cast<float4*>(lds + (c << 5) + ((j ^ (c & 7)) << 2)) = v;
}

// one DF2T step; updates z0..z4, sets yv (10 fma + 1 mul)
#define STEP(xv) do {                               \
    float y_ = fmaf(b0, (xv), z0);                  \
    z0 = fmaf(na1, y_, fmaf(b1, (xv), z1));         \
    z1 = fmaf(na2, y_, fmaf(b2, (xv), z2));         \
    z2 = fmaf(na3, y_, fmaf(b3, (xv), z3));         \
    z3 = fmaf(na4, y_, fmaf(b4, (xv), z4));         \
    z4 = fmaf(na5, y_, b5 * (xv));                  \
    yv = y_;                                        \
} while (0)

__global__ __launch_bounds__(TPB, 4) void GREEN_62869731278967_filtfilt(
    const float* __restrict__ x,
    const float* __restrict__ bc,
    const float* __restrict__ ac,
    const float* __restrict__ zc,
    float* __restrict__ out)
{
    __shared__ float lds[NN];            // 32768 B exactly
    const int row = blockIdx.x;
    const int tid = threadIdx.x;
    const float* xr   = x   + (size_t)row * NN;
    float*       outr = out + (size_t)row * NN;

    const float b0 = bc[0], b1 = bc[1], b2 = bc[2], b3 = bc[3], b4 = bc[4], b5 = bc[5];
    const float na1 = -ac[1], na2 = -ac[2], na3 = -ac[3], na4 = -ac[4], na5 = -ac[5];
    const float zi0 = zc[0], zi1 = zc[1], zi2 = zc[2], zi3 = zc[3], zi4 = zc[4];

    // ---- Phase A: HBM -> LDS via global_load_lds, pre-swizzled source ----
    // lane L of wave wv, issue k: LDS dest words [2048*wv + 256*k + 4*L, +4)
    // source float offset = 2048*wv + 256*k + 32*(L>>3) + 4*((L&7)^(L>>3))
    {
        const int wv = tid >> 6, L = tid & 63;
        const float* srow = xr + ((wv << 11) + ((L >> 3) << 5) + (((L & 7) ^ (L >> 3)) << 2));
        float* lbase = lds + (wv << 11);
#pragma unroll
        for (int k = 0; k < 8; ++k)
            gload16(srow + (k << 8), lbase + (k << 8));
    }
    asm volatile("s_waitcnt vmcnt(0)" ::: "memory");
    __syncthreads();                     // x ready

    float yreg[LC];
    float ytail[PADL];                   // only tid == 255 uses
    float z0, z1, z2, z3, z4, yv;

    // ---- forward: warm over chunk tid-1, filter own chunk -> yreg ----
    if (tid == 0) {
        // exact reference path (chunk 0 is linear in LDS)
        const float x0 = lds[0];
        float v0 = 2.f * x0 - lds[PADL];
        z0 = zi0 * v0; z1 = zi1 * v0; z2 = zi2 * v0; z3 = zi3 * v0; z4 = zi4 * v0;
#pragma unroll
        for (int t = 0; t < PADL; ++t) {
            float v = 2.f * x0 - lds[PADL - t];
            STEP(v);
        }
    } else {
        float v0 = SC(lds, tid - 1, 0);
        z0 = zi0 * v0; z1 = zi1 * v0; z2 = zi2 * v0; z3 = zi3 * v0; z4 = zi4 * v0;
#pragma unroll
        for (int j = 0; j < 8; ++j) {
            float4 q = LDQ(lds, tid - 1, j);
            STEP(q.x); STEP(q.y); STEP(q.z); STEP(q.w);
        }
    }
#pragma unroll
    for (int j = 0; j < 8; ++j) {
        float4 q = LDQ(lds, tid, j);
        STEP(q.x); yreg[4 * j + 0] = yv;
        STEP(q.y); yreg[4 * j + 1] = yv;
        STEP(q.z); yreg[4 * j + 2] = yv;
        STEP(q.w); yreg[4 * j + 3] = yv;
    }
    if (tid == TPB - 1) {
        // tail y[8210..8227): ext = 2*xN - x[8190-i]  (chunk 255, elem 30-i)
        const float xN = SC(lds, TPB - 1, 31);
#pragma unroll
        for (int i = 0; i < PADL; ++i) {
            float v = 2.f * xN - SC(lds, TPB - 1, 30 - i);
            STEP(v);
            ytail[i] = yv;
        }
    }
    __syncthreads();                     // all forward x-reads done

    // ---- exchange: overwrite LDS chunk tid with y (b128 writes) ----
#pragma unroll
    for (int j = 0; j < 8; ++j)
        STQ(lds, tid, j, make_float4(yreg[4 * j], yreg[4 * j + 1],
                                     yreg[4 * j + 2], yreg[4 * j + 3]));
    __syncthreads();                     // y ready

    // ---- backward: warm descending over chunk tid+1's y, own from regs ----
    if (tid == TPB - 1) {
        float u0 = ytail[PADL - 1];
        z0 = zi0 * u0; z1 = zi1 * u0; z2 = zi2 * u0; z3 = zi3 * u0; z4 = zi4 * u0;
#pragma unroll
        for (int s = 0; s < PADL; ++s) STEP(ytail[PADL - 1 - s]);
    } else {
        float u0 = SC(lds, tid + 1, LC - 1);
        z0 = zi0 * u0; z1 = zi1 * u0; z2 = zi2 * u0; z3 = zi3 * u0; z4 = zi4 * u0;
#pragma unroll
        for (int j = 7; j >= 0; --j) {
            float4 q = LDQ(lds, tid + 1, j);
            STEP(q.w); STEP(q.z); STEP(q.y); STEP(q.x);
        }
    }
#pragma unroll
    for (int i = 0; i < LC; ++i) { STEP(yreg[LC - 1 - i]); yreg[LC - 1 - i] = yv; }

    // ---- store (float4) ----
#pragma unroll
    for (int q = 0; q < LC / 4; ++q) {
        float4 v;
        v.x = yreg[4 * q + 0];
        v.y = yreg[4 * q + 1];
        v.z = yreg[4 * q + 2];
        v.w = yreg[4 * q + 3];
        *reinterpret_cast<float4*>(outr + tid * LC + 4 * q) = v;
    }
}

extern "C" void kernel_launch(void* const* d_in, const int* in_sizes, int n_in,
                              void* d_out, int out_size, void* d_ws, size_t ws_size,
                              hipStream_t stream) {
    const float* x  = (const float*)d_in[0];
    const float* b  = (const float*)d_in[1];
    const float* a  = (const float*)d_in[2];
    const float* zi = (const float*)d_in[3];
    float* out = (float*)d_out;
    const int rows = in_sizes[0] / NN;   // 4096
    GREEN_62869731278967_filtfilt<<<rows, TPB, 0, stream>>>(x, b, a, zi, out);
}